// Round 7
// baseline (381.984 us; speedup 1.0000x reference)
//
#include <hip/hip_runtime.h>
#include <hip/hip_bf16.h>

// Pipeline:
//  x (4,64,130,130) --conv3x3 valid + bias + maxpool2x2--> p1 (4,64,64,64)
//  p1 --1x1 conv (64->32)--> t2 (4,32,64,64)
//  t2 --3x3 conv pad=1 (32->32)--> t3 (4,32,64,64)
//  t3 --1x1 conv (32->1152)--> t4 (4,1152,4096)  [CHANNEL-major offset field]
//  deform_conv(x, upsample2x(offsets), wd) -> out (4,64,128,128)
//  Deform: offsets at half res => 2x2 quad shares (fy,fx); 16 bilinear taps
//  collapse to a 3x3 grid. Block = 16-po strip; 2 TEAMS of 128 threads split
//  the input channels (team t: chunks 4t..4t+3) and combine via LDS at the
//  end (no atomics). 8 oc/thread = 32 FMA per ds_read_b128. XCD-pinned:
//  blk&7 = b + 4*(strip&1) -> each XCD's L2 holds one batch's x.

#define HX 130
#define WX 130

// ---------------- K0: wd (o,c,3,3) -> wdt2[(c*9+k)*64 + o]  (k-major)
__global__ __launch_bounds__(256) void k_wdt(const float* __restrict__ wd,
                                             float* __restrict__ wdt2) {
    int idx = blockIdx.x * 256 + threadIdx.x;   // 64*64*9 = 36864
    if (idx >= 36864) return;
    int k = idx % 9;
    int rem = idx / 9;        // o*64 + c
    int c = rem & 63;
    int o = rem >> 6;
    wdt2[(c * 9 + k) * 64 + o] = wd[idx];
}

// ---------------- K1: conv3x3 valid (64->64) + bias + maxpool 2x2 -> p1
// grid 1024 = b(4) * cog(8, 8 oc each) * tile(32, 2 pooled rows); block 128.
__global__ __launch_bounds__(128, 4) void k_conv0_pool(const float* __restrict__ x,
                                                       const float* __restrict__ w0,
                                                       const float* __restrict__ b0,
                                                       float* __restrict__ p1) {
    int idx = blockIdx.x;
    int tile = idx & 31;          // 2 pooled rows each
    int cog = (idx >> 5) & 7;     // blockIdx-derived -> weight loads scalar
    int b = idx >> 8;
    int tid = threadIdx.x;
    int pw = tid & 63;
    int phl = tid >> 6;           // 0..1
    int ph = tile * 2 + phl;
    __shared__ float slab[6 * WX];            // 780 floats
    const float* xb = x + (size_t)(b * 64) * HX * WX;
    int row0 = tile * 4;          // x rows row0..row0+5
    const float* xbase = xb + row0 * WX;
    float acc[8][4];
    #pragma unroll
    for (int i = 0; i < 8; ++i)
        #pragma unroll
        for (int j = 0; j < 4; ++j) acc[i][j] = 0.f;

    float pre[7];
    #pragma unroll
    for (int j = 0; j < 7; ++j) {
        int i = tid + j * 128;
        pre[j] = (i < 6 * WX) ? xbase[i] : 0.f;
    }

    for (int ci = 0; ci < 64; ++ci) {
        __syncthreads();
        #pragma unroll
        for (int j = 0; j < 7; ++j) {
            int i = tid + j * 128;
            if (i < 6 * WX) slab[i] = pre[j];
        }
        __syncthreads();
        if (ci < 63) {
            const float* xp = xbase + (size_t)(ci + 1) * (HX * WX);
            #pragma unroll
            for (int j = 0; j < 7; ++j) {
                int i = tid + j * 128;
                pre[j] = (i < 6 * WX) ? xp[i] : 0.f;
            }
        }
        float v[4][4];
        #pragma unroll
        for (int r2 = 0; r2 < 4; ++r2) {
            const float* rp = &slab[(2 * phl + r2) * WX + 2 * pw];  // 8B aligned
            float2 a = *(const float2*)rp;
            float2 bb = *(const float2*)(rp + 2);
            v[r2][0] = a.x; v[r2][1] = a.y; v[r2][2] = bb.x; v[r2][3] = bb.y;
        }
        #pragma unroll
        for (int i = 0; i < 8; ++i) {
            const float* wp = w0 + (((cog * 8 + i) * 64) + ci) * 9;  // uniform
            float w[9];
            #pragma unroll
            for (int k = 0; k < 9; ++k) w[k] = wp[k];
            #pragma unroll
            for (int dr = 0; dr < 2; ++dr)
                #pragma unroll
                for (int dc = 0; dc < 2; ++dc) {
                    float s = acc[i][dr * 2 + dc];
                    #pragma unroll
                    for (int ky = 0; ky < 3; ++ky)
                        #pragma unroll
                        for (int kx = 0; kx < 3; ++kx)
                            s += w[ky * 3 + kx] * v[dr + ky][dc + kx];
                    acc[i][dr * 2 + dc] = s;
                }
        }
    }
    #pragma unroll
    for (int i = 0; i < 8; ++i) {
        float m = fmaxf(fmaxf(acc[i][0], acc[i][1]), fmaxf(acc[i][2], acc[i][3]))
                + b0[cog * 8 + i];
        p1[(((size_t)b * 64 + cog * 8 + i) * 64 + ph) * 64 + pw] = m;
    }
}

// ---------------- K2: 1x1 conv 64->32 on 64x64; grid 1024 (2 oc/thread)
__global__ __launch_bounds__(256) void k_conv1x1_a(const float* __restrict__ p1,
                                                   const float* __restrict__ w1,
                                                   const float* __restrict__ b1,
                                                   float* __restrict__ t2) {
    int blk = blockIdx.x;
    int pt = blk & 15;
    int cog = (blk >> 4) & 15;
    int b = blk >> 8;
    int p = pt * 256 + threadIdx.x;
    float acc[2];
    #pragma unroll
    for (int i = 0; i < 2; ++i) acc[i] = b1[cog * 2 + i];
    const float* ip = p1 + (size_t)b * 64 * 4096 + p;
    for (int ci = 0; ci < 64; ++ci) {
        float v = ip[(size_t)ci * 4096];
        #pragma unroll
        for (int i = 0; i < 2; ++i) acc[i] += w1[(cog * 2 + i) * 64 + ci] * v;
    }
    float* op = t2 + (size_t)b * 32 * 4096 + p;
    #pragma unroll
    for (int i = 0; i < 2; ++i) op[(size_t)(cog * 2 + i) * 4096] = acc[i];
}

// ---------------- K3: 3x3 conv pad=1, 32->32 on 64x64; grid 1024 (2 oc/thread)
__global__ __launch_bounds__(256) void k_conv3x3_b(const float* __restrict__ t2,
                                                   const float* __restrict__ w2,
                                                   const float* __restrict__ b2,
                                                   float* __restrict__ t3) {
    int blk = blockIdx.x;
    int pt = blk & 15;
    int cog = (blk >> 4) & 15;
    int b = blk >> 8;
    int p = pt * 256 + threadIdx.x;
    int hy = p >> 6, wx = p & 63;
    float acc[2];
    #pragma unroll
    for (int i = 0; i < 2; ++i) acc[i] = b2[cog * 2 + i];
    const float* ip = t2 + (size_t)b * 32 * 4096;
    for (int ci = 0; ci < 32; ++ci) {
        float v[9];
        #pragma unroll
        for (int ky = 0; ky < 3; ++ky) {
            int yy = hy + ky - 1;
            #pragma unroll
            for (int kx = 0; kx < 3; ++kx) {
                int xx = wx + kx - 1;
                bool ok = (yy >= 0 && yy < 64 && xx >= 0 && xx < 64);
                int yc = min(max(yy, 0), 63), xc = min(max(xx, 0), 63);
                float val = ip[(size_t)ci * 4096 + yc * 64 + xc];
                v[ky * 3 + kx] = ok ? val : 0.f;
            }
        }
        #pragma unroll
        for (int i = 0; i < 2; ++i) {
            const float* wp = w2 + (((cog * 2 + i) * 32) + ci) * 9;   // uniform
            float s = acc[i];
            #pragma unroll
            for (int k = 0; k < 9; ++k) s += wp[k] * v[k];
            acc[i] = s;
        }
    }
    float* op = t3 + (size_t)b * 32 * 4096 + p;
    #pragma unroll
    for (int i = 0; i < 2; ++i) op[(size_t)(cog * 2 + i) * 4096] = acc[i];
}

// ---------------- K4: 1x1 conv 32->1152, CHANNEL-major t4[b][1152][4096]
// grid 4608 = b(4)*chg(72 groups of 16 ch)*pt(16)
__global__ __launch_bounds__(256) void k_conv1x1_off(const float* __restrict__ t3,
                                                     const float* __restrict__ w3,
                                                     const float* __restrict__ b3,
                                                     float* __restrict__ t4) {
    int blk = blockIdx.x;
    int pt = blk & 15;
    int rem = blk >> 4;           // 0..287
    int chg = rem % 72;           // blockIdx-derived -> scalar weight loads
    int b = rem / 72;
    int p = pt * 256 + threadIdx.x;
    float v[32];
    const float* ip = t3 + (size_t)b * 32 * 4096 + p;
    #pragma unroll
    for (int ci = 0; ci < 32; ++ci) v[ci] = ip[(size_t)ci * 4096];
    float* op = t4 + ((size_t)b * 1152) * 4096 + p;
    #pragma unroll
    for (int j = 0; j < 16; ++j) {
        int ch = chg * 16 + j;
        float acc = b3[ch];
        const float* wp = w3 + ch * 32;      // uniform
        #pragma unroll
        for (int ci = 0; ci < 32; ++ci) acc += wp[ci] * v[ci];
        op[(size_t)ch * 4096] = acc;         // coalesced
    }
}

// ---------------- K5: deformable conv, two teams split input channels in-block
// grid 1024 = strip(256)*4 + b  [blk&7 = b + 4*(strip&1) -> XCD sees one batch]
// block 256 = team(2) x [og(8 x 8oc) x q(16)]; team t does chunks 4t..4t+3.
// LDS 37.4 KB -> 4 blocks/CU = 16 waves/CU. Teams combine via LDS, plain stores.
#define VP 292   // vlds quad pitch in floats (72*4 + 4) -> 2-way (free) conflicts
__global__ __launch_bounds__(256, 4) void k_deform(const float* __restrict__ x,
                                                   const float* __restrict__ t4,
                                                   const float* __restrict__ wdt2,
                                                   float* __restrict__ out) {
    int blk = blockIdx.x;
    int b = blk & 3;
    int strip = blk >> 2;         // 0..255
    int tid = threadIdx.x;
    int team = tid >> 7;          // 0/1
    int tidl = tid & 127;
    int og = tidl >> 4;           // 0..7 (8 out-channels each)
    int q = tidl & 15;            // quad in strip
    int po0 = strip * 16;
    int qy = po0 >> 6;            // strip lies in one quad-row
    int qx0 = po0 & 63;

    __shared__ __align__(16) float vlds[2][16 * VP];   // 37376 B

    float acc[8][4];
    #pragma unroll
    for (int o = 0; o < 8; ++o)
        #pragma unroll
        for (int s = 0; s < 4; ++s) acc[o][s] = 0.f;

    const float* xb = x + (size_t)b * 64 * HX * WX;
    const float* t4b = t4 + (size_t)b * 1152 * 4096 + po0;
    float* vmine = &vlds[team][0];

    for (int c4 = 0; c4 < 4; ++c4) {
        int chunk = team * 4 + c4;
        __syncthreads();          // prev phase2 done with vlds
        // ---- phase 1: 1152 tasks per team (16 q x 72 ckk) = 9 exact iters
        #pragma unroll
        for (int it = 0; it < 9; ++it) {
            int idx = it * 128 + tidl;
            int tq = idx & 15;
            int ckk = idx >> 4;               // 0..71 = ch*9+kk
            int ch = (ckk * 57) >> 9;         // /9
            int kk = ckk - ch * 9;
            int c = chunk * 8 + ch;
            float oy = t4b[(size_t)(chunk * 144 + 2 * ckk) * 4096 + tq];
            float ox = t4b[(size_t)(chunk * 144 + 2 * ckk + 1) * 4096 + tq];
            float py = oy + (float)(2 * qy + kk / 3);
            float px = ox + (float)(2 * (qx0 + tq) + kk % 3);
            float y0f = floorf(py), x0f = floorf(px);
            float fy = py - y0f, fx = px - x0f;
            int y0 = (int)y0f, x0 = (int)x0f;
            const float* xp = xb + (size_t)c * (HX * WX);
            float t[3][3];
            #pragma unroll
            for (int r = 0; r < 3; ++r) {
                int yy = y0 + r;
                bool vy = (yy >= 0) & (yy < HX);
                int yc = min(max(yy, 0), HX - 1);
                #pragma unroll
                for (int sx = 0; sx < 3; ++sx) {
                    int xx = x0 + sx;
                    bool vx = (xx >= 0) & (xx < WX);
                    int xc = min(max(xx, 0), WX - 1);
                    float val = xp[yc * WX + xc];
                    t[r][sx] = (vy & vx) ? val : 0.f;
                }
            }
            float h0[3], h1[3];
            #pragma unroll
            for (int r = 0; r < 3; ++r) {
                h0[r] = t[r][0] + fx * (t[r][1] - t[r][0]);
                h1[r] = t[r][1] + fx * (t[r][2] - t[r][1]);
            }
            float4 vv;
            vv.x = h0[0] + fy * (h0[1] - h0[0]);   // sub (0,0)
            vv.y = h1[0] + fy * (h1[1] - h1[0]);   // sub (0,1)
            vv.z = h0[1] + fy * (h0[2] - h0[1]);   // sub (1,0)
            vv.w = h1[1] + fy * (h1[2] - h1[1]);   // sub (1,1)
            *(float4*)&vmine[tq * VP + ckk * 4] = vv;
        }
        __syncthreads();          // vlds visible (team-symmetric barrier)

        // ---- phase 2: acc[8 outs][4 sub] += w * v  (32 FMA per b128 read)
        for (int ch = 0; ch < 8; ++ch) {
            int c = chunk * 8 + ch;
            const float* wp = wdt2 + (size_t)(c * 9) * 64 + og * 8;
            const float* vp = &vmine[q * VP + (ch * 9) * 4];
            #pragma unroll
            for (int k = 0; k < 9; ++k) {
                float4 vv = *(const float4*)(vp + k * 4);
                float4 wa = *(const float4*)(wp + k * 64);
                float4 wb = *(const float4*)(wp + k * 64 + 4);
                float wv[8] = {wa.x, wa.y, wa.z, wa.w, wb.x, wb.y, wb.z, wb.w};
                #pragma unroll
                for (int o = 0; o < 8; ++o) {
                    acc[o][0] += wv[o] * vv.x;
                    acc[o][1] += wv[o] * vv.y;
                    acc[o][2] += wv[o] * vv.z;
                    acc[o][3] += wv[o] * vv.w;
                }
            }
        }
    }

    // ---- team combine via LDS (stride 36 -> 2-way free conflicts), team0 stores
    __syncthreads();
    float* cb = &vlds[1][0];      // 128*36 = 4608 <= 4672 floats
    if (team == 1) {
        #pragma unroll
        for (int o = 0; o < 8; ++o)
            *(float4*)&cb[tidl * 36 + o * 4] =
                make_float4(acc[o][0], acc[o][1], acc[o][2], acc[o][3]);
    }
    __syncthreads();
    if (team == 0) {
        int ho = 2 * qy, wo = 2 * (qx0 + q);
        #pragma unroll
        for (int o = 0; o < 8; ++o) {
            float4 other = *(const float4*)&cb[tidl * 36 + o * 4];
            float s0 = acc[o][0] + other.x;
            float s1 = acc[o][1] + other.y;
            float s2 = acc[o][2] + other.z;
            float s3 = acc[o][3] + other.w;
            int oc = og * 8 + o;
            float* op = out + (((size_t)b * 64 + oc) * 128 + ho) * 128 + wo;
            *(float2*)op = make_float2(s0, s1);
            *(float2*)(op + 128) = make_float2(s2, s3);
        }
    }
}

extern "C" void kernel_launch(void* const* d_in, const int* in_sizes, int n_in,
                              void* d_out, int out_size, void* d_ws, size_t ws_size,
                              hipStream_t stream) {
    const float* x  = (const float*)d_in[0];
    const float* w0 = (const float*)d_in[1];
    const float* b0 = (const float*)d_in[2];
    const float* w1 = (const float*)d_in[3];
    const float* b1 = (const float*)d_in[4];
    const float* w2 = (const float*)d_in[5];
    const float* b2 = (const float*)d_in[6];
    const float* w3 = (const float*)d_in[7];
    const float* b3 = (const float*)d_in[8];
    const float* wd = (const float*)d_in[9];
    float* out = (float*)d_out;

    float* ws = (float*)d_ws;
    float* p1   = ws;                        // 1,048,576
    float* t2   = p1 + 1048576;              //   524,288
    float* t3   = t2 + 524288;               //   524,288
    float* t4   = t3 + 524288;               // 18,874,368 (channel-major)
    float* wdt2 = t4 + 18874368;             //    36,864 (k-major)

    k_wdt<<<144, 256, 0, stream>>>(wd, wdt2);
    k_conv0_pool<<<1024, 128, 0, stream>>>(x, w0, b0, p1);
    k_conv1x1_a<<<1024, 256, 0, stream>>>(p1, w1, b1, t2);
    k_conv3x3_b<<<1024, 256, 0, stream>>>(t2, w2, b2, t3);
    k_conv1x1_off<<<4608, 256, 0, stream>>>(t3, w3, b3, t4);
    k_deform<<<1024, 256, 0, stream>>>(x, t4, wdt2, out);
}

// Round 8
// 370.078 us; speedup vs baseline: 1.0322x; 1.0322x over previous
//
#include <hip/hip_runtime.h>
#include <hip/hip_bf16.h>

// Pipeline:
//  x (4,64,130,130) --conv3x3 valid + bias + maxpool2x2--> p1 (4,64,64,64)
//  p1 --1x1 conv (64->32)--> t2 (4,32,64,64)
//  t2 --3x3 conv pad=1 (32->32)--> t3 (4,32,64,64)
//  t3 --1x1 conv (32->1152)--> t4blk[b][strip=po/16][1152][16]  (STRIP-BLOCKED)
//  deform_conv(x, upsample2x(offsets), wd) -> out (4,64,128,128)
//  Deform: offsets at half res => 2x2 quad shares (fy,fx); 16 bilinear taps
//  collapse to a 3x3 grid. Block = 16-po strip; per chunk, the block's 2304
//  offset floats are ONE contiguous 9.2KB run of t4blk -> flat coalesced
//  LDS staging with register prefetch. Phase1 computes v once per
//  (quad,ch,kk) into LDS; phase2 = small GEMM from LDS.

#define HX 130
#define WX 130

// ---------------- K0: wd (o,c,3,3) -> wdt2[(c*9+k)*64 + o]  (k-major)
__global__ __launch_bounds__(256) void k_wdt(const float* __restrict__ wd,
                                             float* __restrict__ wdt2) {
    int idx = blockIdx.x * 256 + threadIdx.x;   // 64*64*9 = 36864
    if (idx >= 36864) return;
    int k = idx % 9;
    int rem = idx / 9;        // o*64 + c
    int c = rem & 63;
    int o = rem >> 6;
    wdt2[(c * 9 + k) * 64 + o] = wd[idx];
}

// ---------------- K1: conv3x3 valid (64->64) + bias + maxpool 2x2 -> p1
// grid 1024 = b(4) * cog(8, 8 oc each) * tile(32, 2 pooled rows); block 128.
__global__ __launch_bounds__(128, 4) void k_conv0_pool(const float* __restrict__ x,
                                                       const float* __restrict__ w0,
                                                       const float* __restrict__ b0,
                                                       float* __restrict__ p1) {
    int idx = blockIdx.x;
    int tile = idx & 31;          // 2 pooled rows each
    int cog = (idx >> 5) & 7;     // blockIdx-derived -> weight loads scalar
    int b = idx >> 8;
    int tid = threadIdx.x;
    int pw = tid & 63;
    int phl = tid >> 6;           // 0..1
    int ph = tile * 2 + phl;
    __shared__ float slab[6 * WX];            // 780 floats
    const float* xb = x + (size_t)(b * 64) * HX * WX;
    int row0 = tile * 4;          // x rows row0..row0+5
    const float* xbase = xb + row0 * WX;
    float acc[8][4];
    #pragma unroll
    for (int i = 0; i < 8; ++i)
        #pragma unroll
        for (int j = 0; j < 4; ++j) acc[i][j] = 0.f;

    float pre[7];
    #pragma unroll
    for (int j = 0; j < 7; ++j) {
        int i = tid + j * 128;
        pre[j] = (i < 6 * WX) ? xbase[i] : 0.f;
    }

    for (int ci = 0; ci < 64; ++ci) {
        __syncthreads();
        #pragma unroll
        for (int j = 0; j < 7; ++j) {
            int i = tid + j * 128;
            if (i < 6 * WX) slab[i] = pre[j];
        }
        __syncthreads();
        if (ci < 63) {
            const float* xp = xbase + (size_t)(ci + 1) * (HX * WX);
            #pragma unroll
            for (int j = 0; j < 7; ++j) {
                int i = tid + j * 128;
                pre[j] = (i < 6 * WX) ? xp[i] : 0.f;
            }
        }
        float v[4][4];
        #pragma unroll
        for (int r2 = 0; r2 < 4; ++r2) {
            const float* rp = &slab[(2 * phl + r2) * WX + 2 * pw];  // 8B aligned
            float2 a = *(const float2*)rp;
            float2 bb = *(const float2*)(rp + 2);
            v[r2][0] = a.x; v[r2][1] = a.y; v[r2][2] = bb.x; v[r2][3] = bb.y;
        }
        #pragma unroll
        for (int i = 0; i < 8; ++i) {
            const float* wp = w0 + (((cog * 8 + i) * 64) + ci) * 9;  // uniform
            float w[9];
            #pragma unroll
            for (int k = 0; k < 9; ++k) w[k] = wp[k];
            #pragma unroll
            for (int dr = 0; dr < 2; ++dr)
                #pragma unroll
                for (int dc = 0; dc < 2; ++dc) {
                    float s = acc[i][dr * 2 + dc];
                    #pragma unroll
                    for (int ky = 0; ky < 3; ++ky)
                        #pragma unroll
                        for (int kx = 0; kx < 3; ++kx)
                            s += w[ky * 3 + kx] * v[dr + ky][dc + kx];
                    acc[i][dr * 2 + dc] = s;
                }
        }
    }
    #pragma unroll
    for (int i = 0; i < 8; ++i) {
        float m = fmaxf(fmaxf(acc[i][0], acc[i][1]), fmaxf(acc[i][2], acc[i][3]))
                + b0[cog * 8 + i];
        p1[(((size_t)b * 64 + cog * 8 + i) * 64 + ph) * 64 + pw] = m;
    }
}

// ---------------- K2: 1x1 conv 64->32 on 64x64; grid 1024 (2 oc/thread)
__global__ __launch_bounds__(256) void k_conv1x1_a(const float* __restrict__ p1,
                                                   const float* __restrict__ w1,
                                                   const float* __restrict__ b1,
                                                   float* __restrict__ t2) {
    int blk = blockIdx.x;
    int pt = blk & 15;
    int cog = (blk >> 4) & 15;
    int b = blk >> 8;
    int p = pt * 256 + threadIdx.x;
    float acc[2];
    #pragma unroll
    for (int i = 0; i < 2; ++i) acc[i] = b1[cog * 2 + i];
    const float* ip = p1 + (size_t)b * 64 * 4096 + p;
    for (int ci = 0; ci < 64; ++ci) {
        float v = ip[(size_t)ci * 4096];
        #pragma unroll
        for (int i = 0; i < 2; ++i) acc[i] += w1[(cog * 2 + i) * 64 + ci] * v;
    }
    float* op = t2 + (size_t)b * 32 * 4096 + p;
    #pragma unroll
    for (int i = 0; i < 2; ++i) op[(size_t)(cog * 2 + i) * 4096] = acc[i];
}

// ---------------- K3: 3x3 conv pad=1, 32->32 on 64x64; grid 1024 (2 oc/thread)
__global__ __launch_bounds__(256) void k_conv3x3_b(const float* __restrict__ t2,
                                                   const float* __restrict__ w2,
                                                   const float* __restrict__ b2,
                                                   float* __restrict__ t3) {
    int blk = blockIdx.x;
    int pt = blk & 15;
    int cog = (blk >> 4) & 15;
    int b = blk >> 8;
    int p = pt * 256 + threadIdx.x;
    int hy = p >> 6, wx = p & 63;
    float acc[2];
    #pragma unroll
    for (int i = 0; i < 2; ++i) acc[i] = b2[cog * 2 + i];
    const float* ip = t2 + (size_t)b * 32 * 4096;
    for (int ci = 0; ci < 32; ++ci) {
        float v[9];
        #pragma unroll
        for (int ky = 0; ky < 3; ++ky) {
            int yy = hy + ky - 1;
            #pragma unroll
            for (int kx = 0; kx < 3; ++kx) {
                int xx = wx + kx - 1;
                bool ok = (yy >= 0 && yy < 64 && xx >= 0 && xx < 64);
                int yc = min(max(yy, 0), 63), xc = min(max(xx, 0), 63);
                float val = ip[(size_t)ci * 4096 + yc * 64 + xc];
                v[ky * 3 + kx] = ok ? val : 0.f;
            }
        }
        #pragma unroll
        for (int i = 0; i < 2; ++i) {
            const float* wp = w2 + (((cog * 2 + i) * 32) + ci) * 9;   // uniform
            float s = acc[i];
            #pragma unroll
            for (int k = 0; k < 9; ++k) s += wp[k] * v[k];
            acc[i] = s;
        }
    }
    float* op = t3 + (size_t)b * 32 * 4096 + p;
    #pragma unroll
    for (int i = 0; i < 2; ++i) op[(size_t)(cog * 2 + i) * 4096] = acc[i];
}

// ---------------- K4: 1x1 conv 32->1152, STRIP-BLOCKED t4blk[b][s][1152][16]
// grid 4608 = b(4)*chg(72 groups of 16 ch)*pt(16)
__global__ __launch_bounds__(256) void k_conv1x1_off(const float* __restrict__ t3,
                                                     const float* __restrict__ w3,
                                                     const float* __restrict__ b3,
                                                     float* __restrict__ t4blk) {
    int blk = blockIdx.x;
    int pt = blk & 15;
    int rem = blk >> 4;           // 0..287
    int chg = rem % 72;           // blockIdx-derived -> scalar weight loads
    int b = rem / 72;
    int p = pt * 256 + threadIdx.x;
    float v[32];
    const float* ip = t3 + (size_t)b * 32 * 4096 + p;
    #pragma unroll
    for (int ci = 0; ci < 32; ++ci) v[ci] = ip[(size_t)ci * 4096];
    // dest: ((b*256 + p/16)*1152 + ch)*16 + p%16
    float* op = t4blk + ((size_t)(b * 256 + (p >> 4)) * 1152) * 16 + (p & 15);
    #pragma unroll
    for (int j = 0; j < 16; ++j) {
        int ch = chg * 16 + j;
        float acc = b3[ch];
        const float* wp = w3 + ch * 32;      // uniform
        #pragma unroll
        for (int ci = 0; ci < 32; ++ci) acc += wp[ci] * v[ci];
        op[(size_t)ch * 16] = acc;           // 64B per 16-lane group, rows adjacent
    }
}

// ---------------- K5: deformable conv, strip-tiled two-phase LDS structure
// grid 1024 = strip(256)*4 + b  [blk&7 = b + 4*(strip&1) -> XCD sees one batch's x]
// block 256: og = tid>>4 (16 groups of 4 oc), q = tid&15 (quad in strip).
// Offsets: flat contiguous 9.2KB/chunk from t4blk, staged to LDS (pitch 17),
// register-prefetched one chunk ahead. ~28.5 KB LDS.
#define VP 292   // vlds quad pitch in floats (72*4 + 4) -> 2-way (free) conflicts
__global__ __launch_bounds__(256, 4) void k_deform(const float* __restrict__ x,
                                                   const float* __restrict__ t4blk,
                                                   const float* __restrict__ wdt2,
                                                   float* __restrict__ out) {
    int blk = blockIdx.x;
    int b = blk & 3;
    int strip = blk >> 2;         // 0..255
    int tid = threadIdx.x;
    int og = tid >> 4;            // 0..15 (4 out-channels each)
    int q = tid & 15;             // quad in strip
    int po0 = strip * 16;
    int qy = po0 >> 6;            // strip lies in one quad-row
    int qx0 = po0 & 63;

    __shared__ float ofs[144 * 17];                // pitch 17 -> no 4-way conflicts
    __shared__ __align__(16) float vlds[16 * VP];  // [q][ckk*4(+pad)] 18688 B

    float acc[4][4];
    #pragma unroll
    for (int o = 0; o < 4; ++o)
        #pragma unroll
        for (int s = 0; s < 4; ++s) acc[o][s] = 0.f;

    const float* xb = x + (size_t)b * 64 * HX * WX;
    // this block's offsets: 8 chunks x 2304 contiguous floats
    const float* t4s = t4blk + (size_t)(b * 256 + strip) * (1152 * 16);

    // prefetch chunk-0 offsets: flat coalesced, 9 floats/thread
    float pre[9];
    #pragma unroll
    for (int j = 0; j < 9; ++j) pre[j] = t4s[j * 256 + tid];

    for (int chunk = 0; chunk < 8; ++chunk) {
        __syncthreads();          // prev phase1 done w/ ofs, prev phase2 done w/ vlds
        #pragma unroll
        for (int j = 0; j < 9; ++j) {
            int i2 = j * 256 + tid;               // row = i2>>4, col = i2&15
            ofs[(i2 >> 4) * 17 + (i2 & 15)] = pre[j];
        }
        if (chunk < 7) {
            const float* src = t4s + (chunk + 1) * 2304;
            #pragma unroll
            for (int j = 0; j < 9; ++j) pre[j] = src[j * 256 + tid];
        }
        __syncthreads();          // ofs visible

        // ---- phase 1: 1152 tasks (16 q x 72 ckk); 4 unguarded + 1 half-masked
        #pragma unroll
        for (int it = 0; it < 5; ++it) {
            int idx = it * 256 + tid;
            if (it < 4 || tid < 128) {            // 4*256=1024 unguarded; tail 128
                int tq = idx & 15;
                int ckk = idx >> 4;               // 0..71 = ch*9+kk
                int ch = (ckk * 57) >> 9;         // /9
                int kk = ckk - ch * 9;
                int c = chunk * 8 + ch;
                float oy = ofs[(2 * ckk) * 17 + tq];
                float ox = ofs[(2 * ckk + 1) * 17 + tq];
                float py = oy + (float)(2 * qy + kk / 3);
                float px = ox + (float)(2 * (qx0 + tq) + kk % 3);
                float y0f = floorf(py), x0f = floorf(px);
                float fy = py - y0f, fx = px - x0f;
                int y0 = (int)y0f, x0 = (int)x0f;
                const float* xp = xb + (size_t)c * (HX * WX);
                float t[3][3];
                #pragma unroll
                for (int r = 0; r < 3; ++r) {
                    int yy = y0 + r;
                    bool vy = (yy >= 0) & (yy < HX);
                    int yc = min(max(yy, 0), HX - 1);
                    #pragma unroll
                    for (int sx = 0; sx < 3; ++sx) {
                        int xx = x0 + sx;
                        bool vx = (xx >= 0) & (xx < WX);
                        int xc = min(max(xx, 0), WX - 1);
                        float val = xp[yc * WX + xc];
                        t[r][sx] = (vy & vx) ? val : 0.f;
                    }
                }
                float h0[3], h1[3];
                #pragma unroll
                for (int r = 0; r < 3; ++r) {
                    h0[r] = t[r][0] + fx * (t[r][1] - t[r][0]);
                    h1[r] = t[r][1] + fx * (t[r][2] - t[r][1]);
                }
                float4 vv;
                vv.x = h0[0] + fy * (h0[1] - h0[0]);   // sub (0,0)
                vv.y = h1[0] + fy * (h1[1] - h1[0]);   // sub (0,1)
                vv.z = h0[1] + fy * (h0[2] - h0[1]);   // sub (1,0)
                vv.w = h1[1] + fy * (h1[2] - h1[1]);   // sub (1,1)
                *(float4*)&vlds[tq * VP + ckk * 4] = vv;
            }
        }
        __syncthreads();          // vlds visible

        // ---- phase 2: acc[4 outs][4 sub] += w * v  (16 FMA per b128 read)
        for (int ch = 0; ch < 8; ++ch) {
            int c = chunk * 8 + ch;
            const float* wp = wdt2 + (size_t)(c * 9) * 64 + og * 4;
            const float* vp = &vlds[q * VP + (ch * 9) * 4];
            #pragma unroll
            for (int k = 0; k < 9; ++k) {
                float4 vv = *(const float4*)(vp + k * 4);
                float4 w4 = *(const float4*)(wp + k * 64);
                float wv[4] = {w4.x, w4.y, w4.z, w4.w};
                #pragma unroll
                for (int o = 0; o < 4; ++o) {
                    acc[o][0] += wv[o] * vv.x;
                    acc[o][1] += wv[o] * vv.y;
                    acc[o][2] += wv[o] * vv.z;
                    acc[o][3] += wv[o] * vv.w;
                }
            }
        }
    }
    // ---- epilogue
    int ho = 2 * qy, wo = 2 * (qx0 + q);
    #pragma unroll
    for (int o = 0; o < 4; ++o) {
        int oc = og * 4 + o;
        float* op = out + (((size_t)b * 64 + oc) * 128 + ho) * 128 + wo;
        *(float2*)op = make_float2(acc[o][0], acc[o][1]);
        *(float2*)(op + 128) = make_float2(acc[o][2], acc[o][3]);
    }
}

extern "C" void kernel_launch(void* const* d_in, const int* in_sizes, int n_in,
                              void* d_out, int out_size, void* d_ws, size_t ws_size,
                              hipStream_t stream) {
    const float* x  = (const float*)d_in[0];
    const float* w0 = (const float*)d_in[1];
    const float* b0 = (const float*)d_in[2];
    const float* w1 = (const float*)d_in[3];
    const float* b1 = (const float*)d_in[4];
    const float* w2 = (const float*)d_in[5];
    const float* b2 = (const float*)d_in[6];
    const float* w3 = (const float*)d_in[7];
    const float* b3 = (const float*)d_in[8];
    const float* wd = (const float*)d_in[9];
    float* out = (float*)d_out;

    float* ws = (float*)d_ws;
    float* p1    = ws;                       // 1,048,576
    float* t2    = p1 + 1048576;             //   524,288
    float* t3    = t2 + 524288;              //   524,288
    float* t4blk = t3 + 524288;              // 18,874,368 (strip-blocked)
    float* wdt2  = t4blk + 18874368;         //    36,864 (k-major)

    k_wdt<<<144, 256, 0, stream>>>(wd, wdt2);
    k_conv0_pool<<<1024, 128, 0, stream>>>(x, w0, b0, p1);
    k_conv1x1_a<<<1024, 256, 0, stream>>>(p1, w1, b1, t2);
    k_conv3x3_b<<<1024, 256, 0, stream>>>(t2, w2, b2, t3);
    k_conv1x1_off<<<4608, 256, 0, stream>>>(t3, w3, b3, t4blk);
    k_deform<<<1024, 256, 0, stream>>>(x, t4blk, wdt2, out);
}

// Round 9
// 325.293 us; speedup vs baseline: 1.1743x; 1.1377x over previous
//
#include <hip/hip_runtime.h>
#include <hip/hip_bf16.h>
#include <hip/hip_fp16.h>

// Pipeline:
//  x (4,64,130,130) --conv3x3 valid + bias + maxpool2x2--> p1 (4,64,64,64)
//  p1 --1x1 conv (64->32)--> t2 (4,32,64,64)
//  t2 --3x3 conv pad=1 (32->32)--> t3 (4,32,64,64)
//  t3 --1x1 conv (32->1152)--> t4h[b][strip][chunk][ckk][16 po]  fp16 (oy,ox) pairs
//  deform_conv(x, upsample2x(offsets), wd) -> out (4,64,128,128)
//  Deform: offsets at half res => 2x2 quad shares (fy,fx); 16 bilinear taps
//  collapse to a 3x3 grid. Block = 16-po strip; offsets read DIRECT from the
//  strip-blocked fp16 buffer (contiguous 256B/wave loads, hoisted x9 for ILP);
//  2 chunks per barrier; phase2 = small GEMM from LDS.

#define HX 130
#define WX 130

// ---------------- K0: wd (o,c,3,3) -> wdt2[(c*9+k)*64 + o]  (k-major)
__global__ __launch_bounds__(256) void k_wdt(const float* __restrict__ wd,
                                             float* __restrict__ wdt2) {
    int idx = blockIdx.x * 256 + threadIdx.x;   // 64*64*9 = 36864
    if (idx >= 36864) return;
    int k = idx % 9;
    int rem = idx / 9;        // o*64 + c
    int c = rem & 63;
    int o = rem >> 6;
    wdt2[(c * 9 + k) * 64 + o] = wd[idx];
}

// ---------------- K1: conv3x3 valid (64->64) + bias + maxpool 2x2 -> p1
// grid 1024 = b(4) * cog(16, 4 oc) * tile(16, 4 pooled rows); block 256
// -> 4 blocks/CU x 4 waves = 16 waves/CU. 2 ci staged per barrier (10.4 KB).
__global__ __launch_bounds__(256, 4) void k_conv0_pool(const float* __restrict__ x,
                                                       const float* __restrict__ w0,
                                                       const float* __restrict__ b0,
                                                       float* __restrict__ p1) {
    int idx = blockIdx.x;
    int tile = idx & 15;          // 4 pooled rows each
    int cog = (idx >> 4) & 15;    // blockIdx-derived -> weight loads scalar
    int b = idx >> 8;
    int tid = threadIdx.x;
    int pw = tid & 63;
    int phl = tid >> 6;           // 0..3
    int ph = tile * 4 + phl;
    __shared__ float slab[2][10 * WX];        // 2 ci x 1300 floats
    const float* xb = x + (size_t)(b * 64) * HX * WX;
    int row0 = tile * 8;          // x rows row0..row0+9
    const float* xbase = xb + row0 * WX;
    float acc[4][4];
    #pragma unroll
    for (int i = 0; i < 4; ++i)
        #pragma unroll
        for (int j = 0; j < 4; ++j) acc[i][j] = 0.f;

    float pre[11];
    #pragma unroll
    for (int j = 0; j < 11; ++j) {
        int i = tid + j * 256;    // 0..2599 covers both ci slabs
        int ci = i / 1300, off = i - ci * 1300;
        pre[j] = (i < 2600) ? xbase[(size_t)ci * (HX * WX) + off] : 0.f;
    }

    for (int cg = 0; cg < 32; ++cg) {         // 2 ci per stage
        __syncthreads();
        #pragma unroll
        for (int j = 0; j < 11; ++j) {
            int i = tid + j * 256;
            if (i < 2600) ((float*)slab)[i] = pre[j];
        }
        __syncthreads();
        if (cg < 31) {
            const float* xp = xbase + (size_t)(2 * cg + 2) * (HX * WX);
            #pragma unroll
            for (int j = 0; j < 11; ++j) {
                int i = tid + j * 256;
                int ci = i / 1300, off = i - ci * 1300;
                pre[j] = (i < 2600) ? xp[(size_t)ci * (HX * WX) + off] : 0.f;
            }
        }
        #pragma unroll
        for (int lc = 0; lc < 2; ++lc) {
            int ci = 2 * cg + lc;
            float v[4][4];
            #pragma unroll
            for (int r2 = 0; r2 < 4; ++r2) {
                const float* rp = &slab[lc][(2 * phl + r2) * WX + 2 * pw];
                float2 a = *(const float2*)rp;
                float2 bb = *(const float2*)(rp + 2);
                v[r2][0] = a.x; v[r2][1] = a.y; v[r2][2] = bb.x; v[r2][3] = bb.y;
            }
            #pragma unroll
            for (int i = 0; i < 4; ++i) {
                const float* wp = w0 + (((cog * 4 + i) * 64) + ci) * 9;  // uniform
                float w[9];
                #pragma unroll
                for (int k = 0; k < 9; ++k) w[k] = wp[k];
                #pragma unroll
                for (int dr = 0; dr < 2; ++dr)
                    #pragma unroll
                    for (int dc = 0; dc < 2; ++dc) {
                        float s = acc[i][dr * 2 + dc];
                        #pragma unroll
                        for (int ky = 0; ky < 3; ++ky)
                            #pragma unroll
                            for (int kx = 0; kx < 3; ++kx)
                                s += w[ky * 3 + kx] * v[dr + ky][dc + kx];
                        acc[i][dr * 2 + dc] = s;
                    }
            }
        }
    }
    #pragma unroll
    for (int i = 0; i < 4; ++i) {
        float m = fmaxf(fmaxf(acc[i][0], acc[i][1]), fmaxf(acc[i][2], acc[i][3]))
                + b0[cog * 4 + i];
        p1[(((size_t)b * 64 + cog * 4 + i) * 64 + ph) * 64 + pw] = m;
    }
}

// ---------------- K2: 1x1 conv 64->32 on 64x64; grid 1024 (2 oc/thread)
__global__ __launch_bounds__(256) void k_conv1x1_a(const float* __restrict__ p1,
                                                   const float* __restrict__ w1,
                                                   const float* __restrict__ b1,
                                                   float* __restrict__ t2) {
    int blk = blockIdx.x;
    int pt = blk & 15;
    int cog = (blk >> 4) & 15;
    int b = blk >> 8;
    int p = pt * 256 + threadIdx.x;
    float acc[2];
    #pragma unroll
    for (int i = 0; i < 2; ++i) acc[i] = b1[cog * 2 + i];
    const float* ip = p1 + (size_t)b * 64 * 4096 + p;
    for (int ci = 0; ci < 64; ++ci) {
        float v = ip[(size_t)ci * 4096];
        #pragma unroll
        for (int i = 0; i < 2; ++i) acc[i] += w1[(cog * 2 + i) * 64 + ci] * v;
    }
    float* op = t2 + (size_t)b * 32 * 4096 + p;
    #pragma unroll
    for (int i = 0; i < 2; ++i) op[(size_t)(cog * 2 + i) * 4096] = acc[i];
}

// ---------------- K3: 3x3 conv pad=1, 32->32 on 64x64; grid 1024 (2 oc/thread)
__global__ __launch_bounds__(256) void k_conv3x3_b(const float* __restrict__ t2,
                                                   const float* __restrict__ w2,
                                                   const float* __restrict__ b2,
                                                   float* __restrict__ t3) {
    int blk = blockIdx.x;
    int pt = blk & 15;
    int cog = (blk >> 4) & 15;
    int b = blk >> 8;
    int p = pt * 256 + threadIdx.x;
    int hy = p >> 6, wx = p & 63;
    float acc[2];
    #pragma unroll
    for (int i = 0; i < 2; ++i) acc[i] = b2[cog * 2 + i];
    const float* ip = t2 + (size_t)b * 32 * 4096;
    for (int ci = 0; ci < 32; ++ci) {
        float v[9];
        #pragma unroll
        for (int ky = 0; ky < 3; ++ky) {
            int yy = hy + ky - 1;
            #pragma unroll
            for (int kx = 0; kx < 3; ++kx) {
                int xx = wx + kx - 1;
                bool ok = (yy >= 0 && yy < 64 && xx >= 0 && xx < 64);
                int yc = min(max(yy, 0), 63), xc = min(max(xx, 0), 63);
                float val = ip[(size_t)ci * 4096 + yc * 64 + xc];
                v[ky * 3 + kx] = ok ? val : 0.f;
            }
        }
        #pragma unroll
        for (int i = 0; i < 2; ++i) {
            const float* wp = w2 + (((cog * 2 + i) * 32) + ci) * 9;   // uniform
            float s = acc[i];
            #pragma unroll
            for (int k = 0; k < 9; ++k) s += wp[k] * v[k];
            acc[i] = s;
        }
    }
    float* op = t3 + (size_t)b * 32 * 4096 + p;
    #pragma unroll
    for (int i = 0; i < 2; ++i) op[(size_t)(cog * 2 + i) * 4096] = acc[i];
}

// ---------------- K4: 1x1 conv 32->1152 -> fp16 (oy,ox)-paired strip-blocked
// t4h[b][strip][chunk(8)][ckk(72)][po(16)] as __half2.  grid 4608.
__global__ __launch_bounds__(256) void k_conv1x1_off(const float* __restrict__ t3,
                                                     const float* __restrict__ w3,
                                                     const float* __restrict__ b3,
                                                     __half2* __restrict__ t4h) {
    int blk = blockIdx.x;
    int pt = blk & 15;
    int rem = blk >> 4;           // 0..287
    int chg = rem % 72;           // blockIdx-derived -> scalar weight loads
    int b = rem / 72;
    int p = pt * 256 + threadIdx.x;
    float v[32];
    const float* ip = t3 + (size_t)b * 32 * 4096 + p;
    #pragma unroll
    for (int ci = 0; ci < 32; ++ci) v[ci] = ip[(size_t)ci * 4096];
    int strip = p >> 4, pl = p & 15;
    __half2* base = t4h + (size_t)(b * 256 + strip) * 9216;   // 8*1152 half2
    #pragma unroll
    for (int m = 0; m < 8; ++m) {
        int chE = chg * 16 + 2 * m;
        float accE = b3[chE], accO = b3[chE + 1];
        const float* wpE = w3 + chE * 32;         // uniform
        const float* wpO = wpE + 32;
        #pragma unroll
        for (int ci = 0; ci < 32; ++ci) {
            accE += wpE[ci] * v[ci];
            accO += wpO[ci] * v[ci];
        }
        int gp = chg * 8 + m;                     // global pair 0..575
        int chunk = gp / 72;
        int ckk = gp - chunk * 72;
        base[chunk * 1152 + ckk * 16 + pl] = __floats2half2_rn(accE, accO);
    }
}

// ---------------- K5: deformable conv
// grid 1024 = strip(256)*4 + b  [blk&7 = b + 4*(strip&1) -> XCD sees one batch's x]
// block 256: og = tid>>4 (16 groups of 4 oc), q = tid&15 (quad in strip).
// 2 chunks per barrier; offsets direct (contiguous fp16), hoisted x9 for ILP.
#define VP 292   // vlds quad pitch in floats (72*4 + 4)
__global__ __launch_bounds__(256, 4) void k_deform(const float* __restrict__ x,
                                                   const __half2* __restrict__ t4h,
                                                   const float* __restrict__ wdt2,
                                                   float* __restrict__ out) {
    int blk = blockIdx.x;
    int b = blk & 3;
    int strip = blk >> 2;         // 0..255
    int tid = threadIdx.x;
    int og = tid >> 4;            // 0..15 (4 out-channels each)
    int q = tid & 15;             // quad in strip
    int po0 = strip * 16;
    int qy = po0 >> 6;            // strip lies in one quad-row
    int qx0 = po0 & 63;

    __shared__ __align__(16) float vlds[2][16 * VP];  // 37376 B

    float acc[4][4];
    #pragma unroll
    for (int o = 0; o < 4; ++o)
        #pragma unroll
        for (int s = 0; s < 4; ++s) acc[o][s] = 0.f;

    const float* xb = x + (size_t)b * 64 * HX * WX;
    const __half2* osrc = t4h + (size_t)(b * 256 + strip) * 9216;

    for (int sup = 0; sup < 4; ++sup) {       // 2 chunks per super-iteration
        __syncthreads();          // prev phase2 done with vlds
        // hoisted offset loads: 2304 tasks = 9 full iters; 256B/wave contiguous
        __half2 o2h[9];
        #pragma unroll
        for (int it = 0; it < 9; ++it)
            o2h[it] = osrc[sup * 2304 + it * 256 + tid];

        #pragma unroll
        for (int it = 0; it < 9; ++it) {
            int idx = it * 256 + tid;         // 0..2303
            int rowg = idx >> 4;              // 0..143
            int tq = idx & 15;
            int lc = rowg >= 72;
            int ckk = rowg - 72 * lc;         // 0..71 = ch*9+kk
            int ch = (ckk * 57) >> 9;         // /9
            int kk = ckk - ch * 9;
            int c = (sup * 2 + lc) * 8 + ch;
            float2 off = __half22float2(o2h[it]);
            float py = off.x + (float)(2 * qy + kk / 3);
            float px = off.y + (float)(2 * (qx0 + tq) + kk % 3);
            float y0f = floorf(py), x0f = floorf(px);
            float fy = py - y0f, fx = px - x0f;
            int y0 = (int)y0f, x0 = (int)x0f;
            const float* xp = xb + (size_t)c * (HX * WX);
            float t[3][3];
            #pragma unroll
            for (int r = 0; r < 3; ++r) {
                int yy = y0 + r;
                bool vy = (yy >= 0) & (yy < HX);
                int yc = min(max(yy, 0), HX - 1);
                #pragma unroll
                for (int sx = 0; sx < 3; ++sx) {
                    int xx = x0 + sx;
                    bool vx = (xx >= 0) & (xx < WX);
                    int xc = min(max(xx, 0), WX - 1);
                    float val = xp[yc * WX + xc];
                    t[r][sx] = (vy & vx) ? val : 0.f;
                }
            }
            float h0[3], h1[3];
            #pragma unroll
            for (int r = 0; r < 3; ++r) {
                h0[r] = t[r][0] + fx * (t[r][1] - t[r][0]);
                h1[r] = t[r][1] + fx * (t[r][2] - t[r][1]);
            }
            float4 vv;
            vv.x = h0[0] + fy * (h0[1] - h0[0]);   // sub (0,0)
            vv.y = h1[0] + fy * (h1[1] - h1[0]);   // sub (0,1)
            vv.z = h0[1] + fy * (h0[2] - h0[1]);   // sub (1,0)
            vv.w = h1[1] + fy * (h1[2] - h1[1]);   // sub (1,1)
            *(float4*)&vlds[lc][tq * VP + ckk * 4] = vv;
        }
        __syncthreads();          // vlds visible

        // ---- phase 2: acc[4 outs][4 sub] += w * v  (16 FMA per b128 read)
        #pragma unroll 1
        for (int lc = 0; lc < 2; ++lc) {
            for (int ch = 0; ch < 8; ++ch) {
                int c = (sup * 2 + lc) * 8 + ch;
                const float* wp = wdt2 + (size_t)(c * 9) * 64 + og * 4;
                const float* vp = &vlds[lc][q * VP + (ch * 9) * 4];
                #pragma unroll
                for (int k = 0; k < 9; ++k) {
                    float4 vv = *(const float4*)(vp + k * 4);
                    float4 w4 = *(const float4*)(wp + k * 64);
                    float wv[4] = {w4.x, w4.y, w4.z, w4.w};
                    #pragma unroll
                    for (int o = 0; o < 4; ++o) {
                        acc[o][0] += wv[o] * vv.x;
                        acc[o][1] += wv[o] * vv.y;
                        acc[o][2] += wv[o] * vv.z;
                        acc[o][3] += wv[o] * vv.w;
                    }
                }
            }
        }
    }
    // ---- epilogue
    int ho = 2 * qy, wo = 2 * (qx0 + q);
    #pragma unroll
    for (int o = 0; o < 4; ++o) {
        int oc = og * 4 + o;
        float* op = out + (((size_t)b * 64 + oc) * 128 + ho) * 128 + wo;
        *(float2*)op = make_float2(acc[o][0], acc[o][1]);
        *(float2*)(op + 128) = make_float2(acc[o][2], acc[o][3]);
    }
}

extern "C" void kernel_launch(void* const* d_in, const int* in_sizes, int n_in,
                              void* d_out, int out_size, void* d_ws, size_t ws_size,
                              hipStream_t stream) {
    const float* x  = (const float*)d_in[0];
    const float* w0 = (const float*)d_in[1];
    const float* b0 = (const float*)d_in[2];
    const float* w1 = (const float*)d_in[3];
    const float* b1 = (const float*)d_in[4];
    const float* w2 = (const float*)d_in[5];
    const float* b2 = (const float*)d_in[6];
    const float* w3 = (const float*)d_in[7];
    const float* b3 = (const float*)d_in[8];
    const float* wd = (const float*)d_in[9];
    float* out = (float*)d_out;

    float* ws = (float*)d_ws;
    float* p1    = ws;                       // 1,048,576 floats
    float* t2    = p1 + 1048576;             //   524,288
    float* t3    = t2 + 524288;              //   524,288
    __half2* t4h = (__half2*)(t3 + 524288);  // 9,437,184 half2 = 37.7 MB
    float* wdt2  = (float*)(t4h + 9437184);  //    36,864 floats

    k_wdt<<<144, 256, 0, stream>>>(wd, wdt2);
    k_conv0_pool<<<1024, 256, 0, stream>>>(x, w0, b0, p1);
    k_conv1x1_a<<<1024, 256, 0, stream>>>(p1, w1, b1, t2);
    k_conv3x3_b<<<1024, 256, 0, stream>>>(t2, w2, b2, t3);
    k_conv1x1_off<<<4608, 256, 0, stream>>>(t3, w3, b3, t4h);
    k_deform<<<1024, 256, 0, stream>>>(x, t4h, wdt2, out);
}